// Round 8
// baseline (475.356 us; speedup 1.0000x reference)
//
#include <hip/hip_runtime.h>
#include <hip/hip_bf16.h>

#define NN 100000
#define DD 128
#define HH 256

#define NBKT 391   // ceil(NN/256) buckets of 256 nodes (bucket = dst>>8)
#define ABLK 128   // partition blocks for phases A/B

typedef _Float16 half_t;
typedef _Float16 half8 __attribute__((ext_vector_type(8)));
typedef _Float16 half4_t __attribute__((ext_vector_type(4)));
typedef float floatx4 __attribute__((ext_vector_type(4)));

// ---------------- CSR build, LDS-atomic counting sort ----------------

// Phase A: per-block bucket histogram; cnt[b*ABLK+blk], tot[b] (tot pre-zeroed)
__global__ __launch_bounds__(256) void hist_bkt(const int* __restrict__ dst,
                                                int* __restrict__ cnt,
                                                int* __restrict__ tot,
                                                int E, int epb) {
    __shared__ int h[NBKT];
    for (int i = threadIdx.x; i < NBKT; i += 256) h[i] = 0;
    __syncthreads();
    int base = blockIdx.x * epb;
    int end = min(base + epb, E);
    for (int e = base + (int)threadIdx.x; e < end; e += 256)
        atomicAdd(&h[dst[e] >> 8], 1);
    __syncthreads();
    for (int i = threadIdx.x; i < NBKT; i += 256) {
        int v = h[i];
        cnt[i * ABLK + blockIdx.x] = v;
        if (v) atomicAdd(&tot[i], v);
    }
}

// exclusive scan of tot[NBKT] -> bktStart[NBKT], bktStart[NBKT]=E
__global__ __launch_bounds__(512) void scan_bkt(const int* __restrict__ tot,
                                                int* __restrict__ bktStart, int E) {
    __shared__ int s[512];
    int t = threadIdx.x;
    int v = (t < NBKT) ? tot[t] : 0;
    s[t] = v;
    __syncthreads();
    for (int off = 1; off < 512; off <<= 1) {
        int u = (t >= off) ? s[t - off] : 0;
        __syncthreads();
        s[t] += u;
        __syncthreads();
    }
    if (t < NBKT) bktStart[t] = s[t] - v;
    if (t == 0) bktStart[NBKT] = E;
}

// per-bucket exclusive scan over blocks -> blockOff[b*ABLK+i]
__global__ __launch_bounds__(128) void scan_blkoff(const int* __restrict__ cnt,
                                                   const int* __restrict__ bktStart,
                                                   int* __restrict__ blockOff) {
    __shared__ int s[128];
    int b = blockIdx.x, t = threadIdx.x;
    int v = cnt[b * ABLK + t];
    s[t] = v;
    __syncthreads();
    for (int off = 1; off < 128; off <<= 1) {
        int u = (t >= off) ? s[t - off] : 0;
        __syncthreads();
        s[t] += u;
        __syncthreads();
    }
    blockOff[b * ABLK + t] = bktStart[b] + s[t] - v;
}

// Phase B: partition edges, packed (src<<8)|(dst&255) (LDS cursors only)
__global__ __launch_bounds__(256) void part_edges(const int* __restrict__ src,
                                                  const int* __restrict__ dst,
                                                  const int* __restrict__ blockOff,
                                                  int* __restrict__ pedge,
                                                  int E, int epb) {
    __shared__ int lbase[NBKT];
    for (int i = threadIdx.x; i < NBKT; i += 256)
        lbase[i] = blockOff[i * ABLK + blockIdx.x];
    __syncthreads();
    int base = blockIdx.x * epb;
    int end = min(base + epb, E);
    for (int e = base + (int)threadIdx.x; e < end; e += 256) {
        int d = dst[e];
        int p = atomicAdd(&lbase[d >> 8], 1);
        pedge[p] = (src[e] << 8) | (d & 255);   // src<2^17, local dst 8 bits
    }
}

// Phase C: per-bucket: node counts -> offsets + dinv + eidx fill (LDS cursors)
__global__ __launch_bounds__(256) void build_csr(const int* __restrict__ pedge,
                                                 const int* __restrict__ bktStart,
                                                 int* __restrict__ offsets,
                                                 float* __restrict__ dinv,
                                                 int* __restrict__ eidx, int N) {
    __shared__ int ncnt[256];
    __shared__ int noff[256];
    __shared__ int cur[256];
    int b = blockIdx.x, t = threadIdx.x;
    int estart = bktStart[b], eend = bktStart[b + 1];
    ncnt[t] = 0;
    __syncthreads();
    for (int e = estart + t; e < eend; e += 256)
        atomicAdd(&ncnt[pedge[e] & 255], 1);
    __syncthreads();
    int c = ncnt[t];
    noff[t] = c;
    __syncthreads();
    for (int off = 1; off < 256; off <<= 1) {
        int u = (t >= off) ? noff[t - off] : 0;
        __syncthreads();
        noff[t] += u;
        __syncthreads();
    }
    int myoff = estart + noff[t] - c;   // exclusive position of node n0+t
    cur[t] = myoff;
    int node = (b << 8) + t;
    if (node < N) {
        offsets[node] = myoff;
        dinv[node] = rsqrtf((float)c + 1.0f);
        if (node == N - 1) offsets[N] = eend;
    }
    __syncthreads();
    for (int e = estart + t; e < eend; e += 256) {
        int v = pedge[e];
        int p = atomicAdd(&cur[v & 255], 1);
        eidx[p] = v >> 8;
    }
}

// ---------------- fp32 -> fp16 convert with per-row dinv scale ----------------
__global__ __launch_bounds__(256) void f2h_scale(const float* __restrict__ in,
                                                 const float* __restrict__ dinv,
                                                 half_t* __restrict__ out, int n4) {
    int i = blockIdx.x * 256 + threadIdx.x;
    if (i < n4) {
        float s = dinv[i >> 5];          // (i*4)/128
        float4 v = ((const float4*)in)[i];
        half4_t o = {(half_t)(v.x * s), (half_t)(v.y * s), (half_t)(v.z * s), (half_t)(v.w * s)};
        ((half4_t*)out)[i] = o;
    }
}

// Wt[c][k] = (half)W[k][c]
__global__ __launch_bounds__(256) void transpose_w(const float* __restrict__ W,
                                                   half_t* __restrict__ Wt, int K, int C) {
    int i = blockIdx.x * 256 + threadIdx.x;
    if (i < K * C) {
        int k = i / C, c = i - k * C;
        Wt[(size_t)c * K + k] = (half_t)W[i];
    }
}

// ---------------- MFMA fp16 GEMM ----------------
// C[r,c] = epilogue( sum_k A[r,k]*Bt[c,k] )
// BIASRELU: relu(acc + bias[c]);  else: acc * dinv[r]
template <int K, int CT, bool BIASRELU>
__global__ __launch_bounds__(256) void gemm_mfma(const half_t* __restrict__ A,
                                                 const half_t* __restrict__ Bt,
                                                 const float* __restrict__ dinv,
                                                 const float* __restrict__ bias,
                                                 half_t* __restrict__ C, int M) {
    constexpr int BK = 64;
    constexpr int LDA = 72;   // halves; 144 B stride -> free 2-way bank aliasing
    __shared__ __align__(16) half_t As[128][LDA];
    __shared__ __align__(16) half_t Bs[64][LDA];

    const int tid = threadIdx.x;
    const int wave = tid >> 6, lane = tid & 63;
    const int wr = wave >> 1, wc = wave & 1;
    const int row0 = blockIdx.y * 128;
    const int col0 = blockIdx.x * 64;
    const int lrow = lane & 15, kq = lane >> 4;

    floatx4 acc[4][2] = {};

    for (int k0 = 0; k0 < K; k0 += BK) {
#pragma unroll
        for (int i = 0; i < 4; ++i) {
            int r = (tid >> 3) + i * 32;
            int kk = (tid & 7) * 8;
            int gr = row0 + r;
            half8 v = {};
            if (gr < M) v = *(const half8*)(A + (size_t)gr * K + k0 + kk);
            *(half8*)&As[r][kk] = v;
        }
#pragma unroll
        for (int i = 0; i < 2; ++i) {
            int n = (tid >> 3) + i * 32;
            int kk = (tid & 7) * 8;
            half8 v = *(const half8*)(Bt + (size_t)(col0 + n) * K + k0 + kk);
            *(half8*)&Bs[n][kk] = v;
        }
        __syncthreads();
#pragma unroll
        for (int ks = 0; ks < 2; ++ks) {
            half8 af[4], bf[2];
#pragma unroll
            for (int i = 0; i < 4; ++i)
                af[i] = *(const half8*)&As[wr * 64 + i * 16 + lrow][ks * 32 + kq * 8];
#pragma unroll
            for (int j = 0; j < 2; ++j)
                bf[j] = *(const half8*)&Bs[wc * 32 + j * 16 + lrow][ks * 32 + kq * 8];
#pragma unroll
            for (int i = 0; i < 4; ++i)
#pragma unroll
                for (int j = 0; j < 2; ++j)
                    acc[i][j] = __builtin_amdgcn_mfma_f32_16x16x32_f16(af[i], bf[j], acc[i][j], 0, 0, 0);
        }
        __syncthreads();
    }

    // C/D layout: col = lane&15, row = (lane>>4)*4 + reg
#pragma unroll
    for (int i = 0; i < 4; ++i) {
#pragma unroll
        for (int r = 0; r < 4; ++r) {
            int grow = row0 + wr * 64 + i * 16 + kq * 4 + r;
            if (grow < M) {
                float s = BIASRELU ? 0.f : dinv[grow];
#pragma unroll
                for (int j = 0; j < 2; ++j) {
                    int gcol = col0 + wc * 32 + j * 16 + lrow;
                    float v = acc[i][j][r];
                    if (BIASRELU) v = fmaxf(v + bias[gcol], 0.f);
                    else          v = v * s;
                    C[(size_t)grow * CT + gcol] = (half_t)v;
                }
            }
        }
    }
}

// ---------------- XCD-aware channel-sliced CSR gather-reduce ----------------
// 128 fp16 channels split into 4 slices of 32 ch (one 64B line each).
// slice = blockIdx&3 -> under round-robin blockIdx%8 XCD dispatch, slice s
// lands on XCDs {s, s+4}: per-XCD y-footprint = 1/4 of rows' bytes.
// 8 lanes per node-slice, half4 per lane; 32 node-slices per 256-thr block.
template <bool OUT16>
__global__ __launch_bounds__(256) void gather_slice(const half_t* __restrict__ y,
                                                    void* __restrict__ outv,
                                                    const int* __restrict__ offsets,
                                                    const int* __restrict__ eidx,
                                                    const float* __restrict__ dinv,
                                                    const float* __restrict__ bias, int N) {
    int slice = blockIdx.x & 3;
    int node = (blockIdx.x >> 2) * 32 + (threadIdx.x >> 3);
    if (node >= N) return;
    int c = slice * 32 + (threadIdx.x & 7) * 4;

    half4_t sv = *(const half4_t*)(y + (size_t)node * DD + c);   // self loop
    float a0 = (float)sv[0], a1 = (float)sv[1], a2 = (float)sv[2], a3 = (float)sv[3];
    float b0 = 0.f, b1_ = 0.f, b2_ = 0.f, b3 = 0.f;

    int e = offsets[node];
    const int e1 = offsets[node + 1];
    for (; e + 3 < e1; e += 4) {
        int s0 = eidx[e], s1 = eidx[e + 1], s2 = eidx[e + 2], s3 = eidx[e + 3];
        half4_t v0 = *(const half4_t*)(y + (size_t)s0 * DD + c);
        half4_t v1 = *(const half4_t*)(y + (size_t)s1 * DD + c);
        half4_t v2 = *(const half4_t*)(y + (size_t)s2 * DD + c);
        half4_t v3 = *(const half4_t*)(y + (size_t)s3 * DD + c);
        a0 += (float)v0[0]; a1 += (float)v0[1]; a2 += (float)v0[2]; a3 += (float)v0[3];
        b0 += (float)v1[0]; b1_ += (float)v1[1]; b2_ += (float)v1[2]; b3 += (float)v1[3];
        a0 += (float)v2[0]; a1 += (float)v2[1]; a2 += (float)v2[2]; a3 += (float)v2[3];
        b0 += (float)v3[0]; b1_ += (float)v3[1]; b2_ += (float)v3[2]; b3 += (float)v3[3];
    }
    for (; e < e1; ++e) {
        int s0 = eidx[e];
        half4_t v0 = *(const half4_t*)(y + (size_t)s0 * DD + c);
        a0 += (float)v0[0]; a1 += (float)v0[1]; a2 += (float)v0[2]; a3 += (float)v0[3];
    }

    float s = dinv[node];
    float o0 = s * (a0 + b0);
    float o1 = s * (a1 + b1_);
    float o2 = s * (a2 + b2_);
    float o3 = s * (a3 + b3);
    if (OUT16) {
        half4_t o = {(half_t)o0, (half_t)o1, (half_t)o2, (half_t)o3};
        *(half4_t*)((half_t*)outv + (size_t)node * DD + c) = o;
    } else {
        float4 bb = *(const float4*)(bias + c);
        float4 o = make_float4(o0 + bb.x, o1 + bb.y, o2 + bb.z, o3 + bb.w);
        *(float4*)((float*)outv + (size_t)node * DD + c) = o;
    }
}

extern "C" void kernel_launch(void* const* d_in, const int* in_sizes, int n_in,
                              void* d_out, int out_size, void* d_ws, size_t ws_size,
                              hipStream_t stream) {
    const float* emb = (const float*)d_in[0];
    const float* W1  = (const float*)d_in[1];
    const float* b1  = (const float*)d_in[2];
    const float* W2  = (const float*)d_in[3];
    const float* b2  = (const float*)d_in[4];
    const int*   ei  = (const int*)d_in[5];

    const int N = NN;
    const int E = in_sizes[5] / 2;
    const int* src = ei;
    const int* dst = ei + E;

    // workspace layout (bytes)
    char* w = (char*)d_ws;
    float*  dinv = (float*)w;  w += 100032 * 4;
    half_t* zh   = (half_t*)w; w += (size_t)NN * DD * 2;   // emb*dinv; reused as y2
    half_t* g1h  = (half_t*)w; w += (size_t)NN * DD * 2;   // aggregated z
    half_t* x1h  = (half_t*)w; w += (size_t)NN * HH * 2;   // layer-1 output
    half_t* W1t  = (half_t*)w; w += (size_t)DD * HH * 2;
    half_t* W2t  = (half_t*)w; w += (size_t)HH * DD * 2;
    int* offsets = (int*)w;    w += 100032 * 4;
    int* cnt     = (int*)w;    w += (size_t)NBKT * ABLK * 4;
    int* blockOff= (int*)w;    w += (size_t)NBKT * ABLK * 4;
    int* tot     = (int*)w;    w += 512 * 4;
    int* bktStart= (int*)w;    w += 512 * 4;
    int* pedge   = (int*)w;    w += (size_t)E * 4;
    int* eidx    = (int*)w;
    float* out   = (float*)d_out;
    half_t* y2h  = zh;         // zh dead after gather1

    const int epb = (E + ABLK - 1) / ABLK;

    // 1. CSR build (all per-edge atomics in LDS)
    hipMemsetAsync(tot, 0, NBKT * sizeof(int), stream);
    hist_bkt<<<ABLK, 256, 0, stream>>>(dst, cnt, tot, E, epb);
    scan_bkt<<<1, 512, 0, stream>>>(tot, bktStart, E);
    scan_blkoff<<<NBKT, 128, 0, stream>>>(cnt, bktStart, blockOff);
    part_edges<<<ABLK, 256, 0, stream>>>(src, dst, blockOff, pedge, E, epb);
    build_csr<<<NBKT, 256, 0, stream>>>(pedge, bktStart, offsets, dinv, eidx, N);

    // 2. z = emb * dinv[row] (fp16) + weight transposes
    f2h_scale<<<(NN * DD / 4 + 255) / 256, 256, 0, stream>>>(emb, dinv, zh, NN * DD / 4);
    transpose_w<<<(DD * HH + 255) / 256, 256, 0, stream>>>(W1, W1t, DD, HH);
    transpose_w<<<(HH * DD + 255) / 256, 256, 0, stream>>>(W2, W2t, HH, DD);

    const int gy = (N + 127) / 128;
    const int aggBlocks = 4 * ((N + 31) / 32);

    // 3. layer 1: aggregate-first (g1 = dinv*(z_self + sum z_src)), then GEMM w/ bias+relu
    gather_slice<true><<<aggBlocks, 256, 0, stream>>>(zh, g1h, offsets, eidx, dinv, nullptr, N);
    gemm_mfma<DD, HH, true><<<dim3(HH / 64, gy), 256, 0, stream>>>(g1h, W1t, dinv, b1, x1h, N);

    // 4. layer 2: GEMM-first (y2 = (x1@W2)*dinv), gather straight into d_out (fp32)
    gemm_mfma<HH, DD, false><<<dim3(DD / 64, gy), 256, 0, stream>>>(x1h, W2t, dinv, nullptr, y2h, N);
    gather_slice<false><<<aggBlocks, 256, 0, stream>>>(y2h, (void*)out, offsets, eidx, dinv, b2, N);
}